// Round 1
// baseline (2614.198 us; speedup 1.0000x reference)
//
#include <hip/hip_runtime.h>

#define Bn 256
#define Tn 2048
#define Dn 40
#define Hn 128
#define Cn 35

typedef _Float16 h2 __attribute__((ext_vector_type(2)));

__device__ __forceinline__ int sdot4(int a, int b, int c) {
#if __has_builtin(__builtin_amdgcn_sdot4)
  return __builtin_amdgcn_sdot4(a, b, c, false);
#else
  int r = c;
#pragma unroll
  for (int i = 0; i < 4; ++i)
    r += ((int)(a << (24 - 8 * i)) >> 24) * ((int)(b << (24 - 8 * i)) >> 24);
  return r;
#endif
}

__device__ __forceinline__ float fdot2f(h2 a, h2 b, float c) {
#if __has_builtin(__builtin_amdgcn_fdot2)
  return __builtin_amdgcn_fdot2(a, b, c, false);
#else
  return c + (float)(a[0]) * (float)(b[0]) + (float)(a[1]) * (float)(b[1]);
#endif
}

__device__ __forceinline__ h2 bch(int u) { return __builtin_bit_cast(h2, u); }

__device__ __forceinline__ int pk2i(float a, float b) {  // two f16 in one word
  h2 r; r[0] = (_Float16)a; r[1] = (_Float16)b;
  return __builtin_bit_cast(int, r);
}

__device__ __forceinline__ float rcpf_(float x) {
#if __has_builtin(__builtin_amdgcn_rcpf)
  return __builtin_amdgcn_rcpf(x);
#else
  return 1.f / x;
#endif
}

__device__ __forceinline__ float sigm(float v) {
  v = fmaxf(fminf(v, 60.f), -60.f);
  return rcpf_(1.f + __expf(-v));
}

__device__ __forceinline__ float tanha(float v) {
  v = fmaxf(fminf(v, 15.f), -15.f);
  const float e = __expf(2.f * v);
  return (e - 1.f) * rcpf_(e + 1.f);
}

__device__ __forceinline__ int q8c(float v) {  // round+clamp to [-127,127]
  v = fminf(fmaxf(v, -127.f), 127.f);
  return (int)__builtin_rintf(v);
}

__device__ __forceinline__ int pk4(int a, int b, int c, int d) {
  return (a & 255) | ((b & 255) << 8) | ((c & 255) << 16) | (d << 24);
}

#if __has_builtin(__builtin_amdgcn_global_load_lds)
#define HAVE_GLDS 1
__device__ __forceinline__ void gl_lds16(const float* g, float* l) {
  __builtin_amdgcn_global_load_lds(
      (const __attribute__((address_space(1))) unsigned int*)(const void*)g,
      (__attribute__((address_space(3))) unsigned int*)(void*)l, 16, 0, 0);
}
#endif

// quantize 128 f32 weights -> 32 packed-i8 words + scale (rowmax/127)
__device__ __forceinline__ void quantW128(const float* __restrict__ p,
                                          int* __restrict__ q, float& sc) {
  float m = 1e-30f;
#pragma unroll
  for (int i = 0; i < 32; ++i) {
    const float4 v = reinterpret_cast<const float4*>(p)[i];
    m = fmaxf(m, fmaxf(fmaxf(fabsf(v.x), fabsf(v.y)),
                       fmaxf(fabsf(v.z), fabsf(v.w))));
  }
  const float inv = 127.f / m;
  sc = m * (1.f / 127.f);
#pragma unroll
  for (int i = 0; i < 32; ++i) {
    const float4 v = reinterpret_cast<const float4*>(p)[i];
    q[i] = pk4(q8c(v.x * inv), q8c(v.y * inv), q8c(v.z * inv), q8c(v.w * inv));
  }
}

// readlane word w (0..319) from 5-reg stash (lane L holds flat[L+64k])
#define RLST(w) __builtin_amdgcn_readlane(                                  \
    ((w) < 64 ? st0 : (w) < 128 ? st1 : (w) < 192 ? st2 : (w) < 256 ? st3  \
                                                        : st4), (w) & 63)

// r7: single-barrier fused step. r6 (2512us, VALUBusy 35%) spent ~2/3 of the
// 2900cy step in chain stalls: 2 barriers + gates round-tripping through LDS
// (s_p0/s_p1) + a serialized U phase. Remap: waves 0-3 = L0, waves 4-7 = L1;
// lane<32 computes gates (i,f), lane>=32 (g,o) for unit 32w+(l&31). After the
// sdot4 dot, one shfl_xor(32) pair exchanges gates within the wave; both
// lanes redundantly compute the (bit-identical) cell update in REGISTERS.
// h stash is double-buffered (no WAR race) -> exactly ONE barrier per step,
// ONE LDS round trip (the stash). Raw s_barrier + lgkmcnt(0) (not
// __syncthreads) so the tl==12 glds prefetch is NOT drained at that step's
// barrier; the vmcnt(0) wait sits in tl==13's converter (per-wave correct:
// each converting wave reads only the s_xraw region its own glds wrote).
// L1 keeps the 1-step lag (iteration t: h0(t) and h1(t-1) from the SAME
// previous stash), epilogue runs the final L1 dot+update in fp32.
__global__ __launch_bounds__(512) void lstm2_fused(
    const float* __restrict__ x,
    const int*   __restrict__ length,
    const float* __restrict__ Wih0, const float* __restrict__ Whh0,
    const float* __restrict__ bih0, const float* __restrict__ bhh0,
    const float* __restrict__ Wih1, const float* __restrict__ Whh1,
    const float* __restrict__ bih1, const float* __restrict__ bhh1,
    const float* __restrict__ gam,  const float* __restrict__ bet,
    const float* __restrict__ fcw,  const float* __restrict__ fcb,
    float* __restrict__ out)
{
  __shared__ int   s_w0x[20][512];                 // 40 KiB w0x f16-pairs SoA
  __shared__ __align__(16) float s_xraw[192 * 4];  // 3 KiB raw x chunk (glds dest)
  __shared__ int   s_xh2[2][320];                  // 2.5 KiB f16 x chunks
  __shared__ float s_xp[2][16][512];               // 64 KiB x-projection
  __shared__ int   s_hq[2][64];                    // double-buffered packed i8 h0|h1
  __shared__ float s_h1f[128];
  __shared__ float s_hn[128];

  const int tid  = threadIdx.x;
  const int lane = tid & 63;
  const int wv   = tid >> 6;          // wave 0..7
  const int b    = blockIdx.x;
  const int len  = length[b];         // 1..2048

  const bool isL1 = (wv >= 4);
  const int  u    = ((wv & 3) << 5) | (lane & 31);     // unit 0..127
  const int  rA   = ((lane < 32) ? 0 : 256) + u;       // gate row A (i or g)
  const int  rB   = rA + 128;                          // gate row B (f or o)

  // ---- kick off chunk-0 x prefetch (waves 0-2; hidden under weight setup) ----
  if (tid < 192) {
    const int seg0 = wv;              // 0..2
    int seg = seg0 * 64 + lane;
    if (seg >= 160) seg = 0;          // clamp (lands in unused s_xraw tail)
#if HAVE_GLDS
    gl_lds16(x + (size_t)b * Tn * Dn + seg * 4, &s_xraw[seg0 * 256]);
#else
    *(float4*)&s_xraw[seg * 4] =
        *(const float4*)(x + (size_t)b * Tn * Dn + seg * 4);
#endif
  }

  // ---- weight setup: each lane owns its TWO gate rows ----
  int qA[32], qB[32], qC[32], qD[32];
  float scA, scB, scC = 0.f, scD = 0.f;
  float biasA, biasB;
  if (!isL1) {
    quantW128(Whh0 + (size_t)rA * Hn, qA, scA);
    quantW128(Whh0 + (size_t)rB * Hn, qB, scB);
    biasA = bih0[rA] + bhh0[rA];
    biasB = bih0[rB] + bhh0[rB];
  } else {
    quantW128(Wih1 + (size_t)rA * Hn, qA, scA);
    quantW128(Wih1 + (size_t)rB * Hn, qB, scB);
    quantW128(Whh1 + (size_t)rA * Hn, qC, scC);
    quantW128(Whh1 + (size_t)rB * Hn, qD, scD);
    biasA = bih1[rA] + bhh1[rA];
    biasB = bih1[rB] + bhh1[rB];
  }
  scA *= (1.f / 127.f);  // fold fixed h-scale (h quantized at 127)
  scB *= (1.f / 127.f);
  scC *= (1.f / 127.f);
  scD *= (1.f / 127.f);
  {  // w0x -> LDS as f16 pairs (slot tid = Wih0 row tid; burst fills slot tid)
    const float* p = Wih0 + (size_t)tid * Dn;
#pragma unroll
    for (int k = 0; k < 20; ++k) s_w0x[k][tid] = pk2i(p[2 * k], p[2 * k + 1]);
  }
  if (tid < 128) s_hq[tid >> 6][tid & 63] = 0;  // both buffers zero
  float creg = 0.f;                             // per-unit cell state (dup x2)
  __syncthreads();  // drains glds; s_w0x/s_xraw/s_hq visible

  // x-projection burst: s_xh2[bb] -> s_xp[bb] (4 passes x 4 rows caps regs)
  auto burst = [&](int bb) {
    const int* flat = &s_xh2[bb][0];
    const int st0 = flat[lane], st1 = flat[lane + 64], st2 = flat[lane + 128],
              st3 = flat[lane + 192], st4 = flat[lane + 256];
#pragma unroll
    for (int pass = 0; pass < 4; ++pass) {
      float a0 = 0.f, a1 = 0.f, a2 = 0.f, a3 = 0.f;
      const int r0 = pass * 4;
#pragma unroll
      for (int g = 0; g < 5; ++g) {
        const h2 w0 = bch(s_w0x[4 * g + 0][tid]);
        const h2 w1 = bch(s_w0x[4 * g + 1][tid]);
        const h2 w2 = bch(s_w0x[4 * g + 2][tid]);
        const h2 w3 = bch(s_w0x[4 * g + 3][tid]);
        a0 = fdot2f(bch(RLST(20 * (r0 + 0) + 4 * g + 0)), w0, a0);
        a0 = fdot2f(bch(RLST(20 * (r0 + 0) + 4 * g + 1)), w1, a0);
        a0 = fdot2f(bch(RLST(20 * (r0 + 0) + 4 * g + 2)), w2, a0);
        a0 = fdot2f(bch(RLST(20 * (r0 + 0) + 4 * g + 3)), w3, a0);
        a1 = fdot2f(bch(RLST(20 * (r0 + 1) + 4 * g + 0)), w0, a1);
        a1 = fdot2f(bch(RLST(20 * (r0 + 1) + 4 * g + 1)), w1, a1);
        a1 = fdot2f(bch(RLST(20 * (r0 + 1) + 4 * g + 2)), w2, a1);
        a1 = fdot2f(bch(RLST(20 * (r0 + 1) + 4 * g + 3)), w3, a1);
        a2 = fdot2f(bch(RLST(20 * (r0 + 2) + 4 * g + 0)), w0, a2);
        a2 = fdot2f(bch(RLST(20 * (r0 + 2) + 4 * g + 1)), w1, a2);
        a2 = fdot2f(bch(RLST(20 * (r0 + 2) + 4 * g + 2)), w2, a2);
        a2 = fdot2f(bch(RLST(20 * (r0 + 2) + 4 * g + 3)), w3, a2);
        a3 = fdot2f(bch(RLST(20 * (r0 + 3) + 4 * g + 0)), w0, a3);
        a3 = fdot2f(bch(RLST(20 * (r0 + 3) + 4 * g + 1)), w1, a3);
        a3 = fdot2f(bch(RLST(20 * (r0 + 3) + 4 * g + 2)), w2, a3);
        a3 = fdot2f(bch(RLST(20 * (r0 + 3) + 4 * g + 3)), w3, a3);
      }
      s_xp[bb][r0 + 0][tid] = a0;
      s_xp[bb][r0 + 1][tid] = a1;
      s_xp[bb][r0 + 2][tid] = a2;
      s_xp[bb][r0 + 3][tid] = a3;
    }
  };

  // ---- chunk 0: convert to f16, project ----
  if (tid < 160) {
    const float4 v = *(const float4*)&s_xraw[4 * tid];
    s_xh2[0][2 * tid]     = pk2i(v.x, v.y);
    s_xh2[0][2 * tid + 1] = pk2i(v.z, v.w);
  }
  __syncthreads();
  burst(0);
  __syncthreads();

#pragma unroll 1
  for (int t = 0; t < len; ++t) {
    const int tl = t & 15;
    const int vq = s_hq[t & 1][lane];  // stash: h0 words 0-31, h1 words 32-63

    if (tl == 12 && tid < 192) {  // async prefetch next raw x chunk
      const int t0 = (t & ~15) + 16;
      if (t0 <= Tn - 16) {
        const int seg0 = wv;
        int seg = seg0 * 64 + lane;
        if (seg >= 160) seg = 0;
#if HAVE_GLDS
        gl_lds16(x + ((size_t)b * Tn + t0) * Dn + seg * 4,
                 &s_xraw[seg0 * 256]);
#else
        *(float4*)&s_xraw[seg * 4] =
            *(const float4*)(x + ((size_t)b * Tn + t0) * Dn + seg * 4);
#endif
      }
    }
    if (tl == 13 && tid < 160) {  // convert own wave's glds data -> f16 chunk
#if HAVE_GLDS
      asm volatile("s_waitcnt vmcnt(0)" ::: "memory");
#endif
      const float4 v = *(const float4*)&s_xraw[4 * tid];
      const int nb = ((t + 3) >> 4) & 1;
      s_xh2[nb][2 * tid]     = pk2i(v.x, v.y);
      s_xh2[nb][2 * tid + 1] = pk2i(v.z, v.w);
    }

    // ---------- fused DOT + update ----------
    float gv1, gv2;
    if (!isL1) {  // g0(t) = Whh0[rA/rB] . h0(t-1) + xproj(t) + bias
      int ia = 0, ia2 = 0, ib = 0, ib2 = 0;
#pragma unroll
      for (int j = 0; j < 32; j += 2) {
        const int s0 = __builtin_amdgcn_readlane(vq, j);
        const int s1 = __builtin_amdgcn_readlane(vq, j + 1);
        ia  = sdot4(s0, qA[j],     ia);
        ib  = sdot4(s0, qB[j],     ib);
        ia2 = sdot4(s1, qA[j + 1], ia2);
        ib2 = sdot4(s1, qB[j + 1], ib2);
      }
      const float xa = s_xp[(t >> 4) & 1][tl][rA];
      const float xb = s_xp[(t >> 4) & 1][tl][rB];
      gv1 = biasA + xa + (float)(ia + ia2) * scA;
      gv2 = biasB + xb + (float)(ib + ib2) * scB;
    } else {  // g1(t-1) = Wih1 . h0(t-1) + Whh1 . h1(t-2) + bias
      int ia = 0, ia2 = 0, ib = 0, ib2 = 0, ic = 0, ic2 = 0, id_ = 0, id2 = 0;
#pragma unroll
      for (int j = 0; j < 32; j += 2) {
        const int s0 = __builtin_amdgcn_readlane(vq, j);
        const int s1 = __builtin_amdgcn_readlane(vq, j + 1);
        ia  = sdot4(s0, qA[j],     ia);
        ib  = sdot4(s0, qB[j],     ib);
        ia2 = sdot4(s1, qA[j + 1], ia2);
        ib2 = sdot4(s1, qB[j + 1], ib2);
      }
#pragma unroll
      for (int j = 0; j < 32; j += 2) {
        const int s0 = __builtin_amdgcn_readlane(vq, 32 + j);
        const int s1 = __builtin_amdgcn_readlane(vq, 33 + j);
        ic  = sdot4(s0, qC[j],     ic);
        id_ = sdot4(s0, qD[j],     id_);
        ic2 = sdot4(s1, qC[j + 1], ic2);
        id2 = sdot4(s1, qD[j + 1], id2);
      }
      gv1 = biasA + (float)(ia + ia2) * scA + (float)(ic + ic2) * scC;
      gv2 = biasB + (float)(ib + ib2) * scB + (float)(id_ + id2) * scD;
    }

    // in-wave gate exchange: partner lane (xor 32) holds the other gate pair
    const float p1 = __shfl_xor(gv1, 32, 64);
    const float p2 = __shfl_xor(gv2, 32, 64);
    const bool  lo = (lane < 32);
    const float gi = lo ? gv1 : p1;
    const float gf = lo ? gv2 : p2;
    const float gg = lo ? p1 : gv1;
    const float go = lo ? p2 : gv2;

    if (!isL1 || t > 0) {  // L1 skips t==0 (h1(-1)=0 must survive in stash)
      creg = sigm(gf) * creg + sigm(gi) * tanha(gg);
      const float h = sigm(go) * tanha(creg);
      if (lo)
        ((signed char*)s_hq)[(((t + 1) & 1) << 8) + (isL1 ? 128 : 0) + u] =
            (signed char)(int)__builtin_rintf(h * 127.f);
    }

    if (tl == 14) burst(((t + 2) >> 4) & 1);  // project next chunk (1/16)

    asm volatile("s_waitcnt lgkmcnt(0)" ::: "memory");  // own LDS writes done
    __builtin_amdgcn_s_barrier();
    __builtin_amdgcn_sched_barrier(0);  // nothing crosses the barrier
  }

  // ---- epilogue: g1(len-1) from final stash -> h1 (fp32) ----
  if (isL1) {
    const int vq = s_hq[len & 1][lane];  // h0(len-1) | h1(len-2)
    int ia = 0, ia2 = 0, ib = 0, ib2 = 0, ic = 0, ic2 = 0, id_ = 0, id2 = 0;
#pragma unroll
    for (int j = 0; j < 32; j += 2) {
      const int s0 = __builtin_amdgcn_readlane(vq, j);
      const int s1 = __builtin_amdgcn_readlane(vq, j + 1);
      ia  = sdot4(s0, qA[j],     ia);
      ib  = sdot4(s0, qB[j],     ib);
      ia2 = sdot4(s1, qA[j + 1], ia2);
      ib2 = sdot4(s1, qB[j + 1], ib2);
    }
#pragma unroll
    for (int j = 0; j < 32; j += 2) {
      const int s0 = __builtin_amdgcn_readlane(vq, 32 + j);
      const int s1 = __builtin_amdgcn_readlane(vq, 33 + j);
      ic  = sdot4(s0, qC[j],     ic);
      id_ = sdot4(s0, qD[j],     id_);
      ic2 = sdot4(s1, qC[j + 1], ic2);
      id2 = sdot4(s1, qD[j + 1], id2);
    }
    float gv1 = biasA + (float)(ia + ia2) * scA + (float)(ic + ic2) * scC;
    float gv2 = biasB + (float)(ib + ib2) * scB + (float)(id_ + id2) * scD;
    const float p1 = __shfl_xor(gv1, 32, 64);
    const float p2 = __shfl_xor(gv2, 32, 64);
    const bool  lo = (lane < 32);
    const float gi = lo ? gv1 : p1;
    const float gf = lo ? gv2 : p2;
    const float gg = lo ? p1 : gv1;
    const float go = lo ? p2 : gv2;
    creg = sigm(gf) * creg + sigm(gi) * tanha(gg);
    const float h = sigm(go) * tanha(creg);
    if (lo) s_h1f[u] = h;
  }
  __syncthreads();

  // ---- LayerNorm over H on wave 0 ----
  if (tid < 64) {
    const float a = s_h1f[tid], d = s_h1f[64 + tid];
    float s = a + d, q = a * a + d * d;
#pragma unroll
    for (int m = 32; m >= 1; m >>= 1) {
      s += __shfl_xor(s, m, 64);
      q += __shfl_xor(q, m, 64);
    }
    const float mu = s * (1.f / 128.f);
    float var = q * (1.f / 128.f) - mu * mu;
    var = fmaxf(var, 0.f);
    const float rstd = rsqrtf(var + 1e-5f);
    s_hn[tid]      = (a - mu) * rstd * gam[tid]      + bet[tid];
    s_hn[64 + tid] = (d - mu) * rstd * gam[64 + tid] + bet[64 + tid];
  }
  __syncthreads();

  // ---- FC head ----
  if (tid < Cn) {
    float acc = fcb[tid];
    const float* wp = fcw + tid * Hn;
#pragma unroll 4
    for (int k = 0; k < Hn; ++k) acc += s_hn[k] * wp[k];
    out[(size_t)b * Cn + tid] = acc;
  }
}

extern "C" void kernel_launch(void* const* d_in, const int* in_sizes, int n_in,
                              void* d_out, int out_size, void* d_ws, size_t ws_size,
                              hipStream_t stream) {
  (void)in_sizes; (void)n_in; (void)d_ws; (void)ws_size; (void)out_size;
  lstm2_fused<<<dim3(Bn), dim3(512), 0, stream>>>(
      (const float*)d_in[0],  (const int*)d_in[1],
      (const float*)d_in[2],  (const float*)d_in[3],
      (const float*)d_in[4],  (const float*)d_in[5],
      (const float*)d_in[6],  (const float*)d_in[7],
      (const float*)d_in[8],  (const float*)d_in[9],
      (const float*)d_in[10], (const float*)d_in[11],
      (const float*)d_in[12], (const float*)d_in[13],
      (float*)d_out);
}